// Round 18
// baseline (2411.857 us; speedup 1.0000x reference)
//
#include <hip/hip_runtime.h>
#include <hip/hip_bf16.h>
#include <math.h>

#define NN 8192
#define DD 256
#define KSEED 5
#define CC 64
#define TK 8
#define NITERS 20
#define CSPLIT 8
#define BM 64
#define BN 64
#define UB 32    // kupd12 gather batch rows
#define NCAND 24 // rescore candidates per row
#define CPAD 257 // LDS centroid row stride (1 mod 32 -> full bank spread)

typedef __attribute__((ext_vector_type(8))) short short8v;
typedef __attribute__((ext_vector_type(4))) float f32x4;

#define MFMA(a, b, c) __builtin_amdgcn_mfma_f32_16x16x32_bf16(a, b, c, 0, 0, 0)

__device__ __forceinline__ bool kbetter(float v1, int i1, float v2, int i2) {
    return (v1 > v2) || ((v1 == v2) && (i1 < i2));
}

__device__ __forceinline__ unsigned short f2bf(float x) {  // RNE
    unsigned u = __float_as_uint(x);
    unsigned r = 0x7fffu + ((u >> 16) & 1u);
    return (unsigned short)((u + r) >> 16);
}
__device__ __forceinline__ float bf2f(unsigned short h) {
    return __uint_as_float(((unsigned)h) << 16);
}

// frag-linear index for element (row, k): row=16T+(l&15), k=32S+8*(l>>4)+j
// -> ((T*8+S)*64 + l)*8 + j
__device__ __forceinline__ size_t fragidx(int row, int k) {
    return (((size_t)(row >> 4) * 8 + (k >> 5)) * 64 + ((k >> 3) & 3) * 16 + (row & 15)) * 8 + (k & 7);
}

// ---------------------------------------------------------------- adjacency bitmap
__global__ __launch_bounds__(256) void adj_k(const int* __restrict__ e0,
                                             const int* __restrict__ e1,
                                             unsigned int* __restrict__ bm, int E) {
    int t = blockIdx.x * 256 + threadIdx.x;
    if (t < E) {
        unsigned code = (unsigned)e0[t] * NN + (unsigned)e1[t];
        atomicOr(&bm[code >> 5], 1u << (code & 31));
    }
}

// ---------------------------------------------------------------- bf16 hi/lo split, fragment-linear layout
__global__ __launch_bounds__(256) void conv_k(const float* __restrict__ src,
                                              short* __restrict__ hi,
                                              short* __restrict__ lo) {
    int slot = blockIdx.x * 256 + threadIdx.x;  // 0..262143
    int l = slot & 63;
    int TS = slot >> 6;
    int S = TS & 7;
    int T = TS >> 3;
    int row = T * 16 + (l & 15);
    int k0 = S * 32 + (l >> 4) * 8;
    const float* p = src + (size_t)row * DD + k0;
    short8v h8, l8;
#pragma unroll
    for (int j = 0; j < 8; j++) {
        float x = p[j];
        unsigned short hb = f2bf(x);
        unsigned short lb = f2bf(x - bf2f(hb));
        h8[j] = (short)hb;
        l8[j] = (short)lb;
    }
    *(short8v*)(hi + (size_t)slot * 8) = h8;
    *(short8v*)(lo + (size_t)slot * 8) = l8;
}

// ---------------------------------------------------------------- kmeans init
__global__ __launch_bounds__(256) void kinit_k(const float* __restrict__ teacher,
                                               const int* __restrict__ initIdx,
                                               float* __restrict__ centR,
                                               float* __restrict__ cnorm,
                                               short* __restrict__ chi,
                                               short* __restrict__ clo) {
    int c = blockIdx.x, s = blockIdx.y;
    int t = threadIdx.x;
    int src = initIdx[s * CC + c];
    float v = teacher[(size_t)src * DD + t];
    centR[((size_t)s * CC + c) * DD + t] = v;
    unsigned short hb = f2bf(v);
    unsigned short lb = f2bf(v - bf2f(hb));
    size_t idx = (size_t)s * 16384 + fragidx(c, t);
    chi[idx] = (short)hb;
    clo[idx] = (short)lb;
    __shared__ float red[256];
    red[t] = v * v;
    __syncthreads();
    for (int w = 128; w > 0; w >>= 1) {
        if (t < w) red[t] += red[t + w];
        __syncthreads();
    }
    if (t == 0) cnorm[s * CC + c] = red[0];
}

// ---------------------------------------------------------------- kmeans assign: MFMA candidates + exact fp32 rescore
// (proven rounds 15-17, absmax 0.0)
__global__ __launch_bounds__(256) void kassign_k(const float* __restrict__ teacher,
                                                 const short* __restrict__ thi,
                                                 const short* __restrict__ tlo,
                                                 const short* __restrict__ chi,
                                                 const short* __restrict__ clo,
                                                 const float* __restrict__ centR,
                                                 const float* __restrict__ cnorm,
                                                 int* __restrict__ labels) {
    __shared__ float cent_s[CC * CPAD];  // 64.25 KB
    __shared__ float cns[CC];
    const int s = blockIdx.y;
    const int pB = blockIdx.x * 64;
    const int tid = threadIdx.x;
    const int w = tid >> 6;
    const int lane = tid & 63;
    const int rl = lane & 15;
    const int lh = lane >> 4;
    // stage centroids: coalesced global read, strided LDS write
    {
        const float* src = centR + (size_t)s * CC * DD;
        for (int u = tid; u < CC * (DD / 4); u += 256) {
            int c = u >> 6;
            int q = (u & 63) << 2;
            float4 v = *(const float4*)&src[c * DD + q];
            float* dst = &cent_s[c * CPAD + q];
            dst[0] = v.x; dst[1] = v.y; dst[2] = v.z; dst[3] = v.w;
        }
    }
    if (tid < CC) cns[tid] = cnorm[s * CC + tid];
    __syncthreads();

    const short* chS = chi + (size_t)s * 16384;
    const short* clS = clo + (size_t)s * 16384;
    const int U = (pB >> 4) + w;  // this wave's point tile

    f32x4 acc[4];  // [cl-tile ct]
#pragma unroll
    for (int ct = 0; ct < 4; ct++) acc[ct] = (f32x4){0.f, 0.f, 0.f, 0.f};

#pragma unroll 1
    for (int S = 0; S < 8; S++) {
        const size_t boff = ((size_t)(U * 8 + S) * 64 + lane) * 8;
        short8v bh = *(const short8v*)(thi + boff);
        short8v bl = *(const short8v*)(tlo + boff);
#pragma unroll
        for (int ct = 0; ct < 4; ct++) {
            const size_t aoff = ((size_t)(ct * 8 + S) * 64 + lane) * 8;
            short8v ah = *(const short8v*)(chS + aoff);
            short8v al = *(const short8v*)(clS + aoff);
            acc[ct] = MFMA(ah, bh, acc[ct]);
            acc[ct] = MFMA(ah, bl, acc[ct]);
            acc[ct] = MFMA(al, bh, acc[ct]);
        }
    }

    // approx candidate: lane's min over its 16 clusters (ct,reg ascending)
    float bd = INFINITY;
    int bc = 0;
#pragma unroll
    for (int ct = 0; ct < 4; ct++)
#pragma unroll
        for (int reg = 0; reg < 4; reg++) {
            int c = 16 * ct + 4 * lh + reg;
            float d = fmaf(-2.f, acc[ct][reg], cns[c]);
            if (d < bd) { bd = d; bc = c; }
        }
    // exact rescore (identical ascending-k fmaf chain; cr from LDS)
    const int gp = pB + 16 * w + rl;
    const float* tr = teacher + (size_t)gp * DD;
    const float* cr = &cent_s[bc * CPAD];
    float dot = 0.f;
    for (int k = 0; k < DD; k += 4) {
        float4 t4 = *(const float4*)&tr[k];
        dot = fmaf(t4.x, cr[k], dot);
        dot = fmaf(t4.y, cr[k + 1], dot);
        dot = fmaf(t4.z, cr[k + 2], dot);
        dot = fmaf(t4.w, cr[k + 3], dot);
    }
    float de = fmaf(-2.f, dot, cns[bc]);
    // exact min with lowest-c tie-break across the 4 lanes of this point
#pragma unroll
    for (int off = 16; off <= 32; off <<= 1) {
        float od = __shfl_xor(de, off, 64);
        int oc = __shfl_xor(bc, off, 64);
        if (od < de || (od == de && oc < bc)) { de = od; bc = oc; }
    }
    if (lh == 0) labels[(size_t)s * NN + gp] = bc;
}

// ---------------------------------------------------------------- fused kmeans update (proven; + frag-linear centroid write)
__global__ __launch_bounds__(256) void kupd12_k(const float* __restrict__ teacher,
                                                const int* __restrict__ labels,
                                                float* __restrict__ centR,
                                                float* __restrict__ cnorm,
                                                short* __restrict__ chi,
                                                short* __restrict__ clo) {
    const int c = blockIdx.x;
    const int s = blockIdx.y;
    const int t = threadIdx.x;
    __shared__ int list[NN];
    __shared__ float stage[UB * DD];
    __shared__ int scan_s[256];
    __shared__ float red[256];
    __shared__ int total_s;

    const int* labS = labels + (size_t)s * NN;

    int my = 0;
#pragma unroll
    for (int j = 0; j < 32; j++) my += (labS[t * 32 + j] == c);
    scan_s[t] = my;
    __syncthreads();
    for (int off = 1; off < 256; off <<= 1) {
        int v = (t >= off) ? scan_s[t - off] : 0;
        __syncthreads();
        scan_s[t] += v;
        __syncthreads();
    }
    const int base = scan_s[t] - my;
    if (t == 255) total_s = scan_s[255];
    int pos = base;
#pragma unroll
    for (int j = 0; j < 32; j++) {
        int p = t * 32 + j;
        if (labS[p] == c) list[pos++] = p;
    }
    __syncthreads();
    const int total = total_s;

    float sum = 0.f, part = 0.f;
    int curb = 0;
    for (int g0 = 0; g0 < total; g0 += UB) {
        const int gn = (total - g0 < UB) ? (total - g0) : UB;
        __syncthreads();
        for (int u = t; u < gn * (DD / 4); u += 256) {
            int j = u >> 6;
            int col4 = (u & 63) << 2;
            *(float4*)&stage[j * DD + col4] =
                *(const float4*)&teacher[(size_t)list[g0 + j] * DD + col4];
        }
        __syncthreads();
        for (int j = 0; j < gn; j++) {
            int p = list[g0 + j];
            int b = p >> 8;
            while (curb < b) { sum += part; part = 0.f; curb++; }
            part += stage[j * DD + t];
        }
    }
    while (curb < 32) { sum += part; part = 0.f; curb++; }

    float old = centR[((size_t)s * CC + c) * DD + t];
    float nv = (total > 0) ? (sum / (float)total) : old;
    centR[((size_t)s * CC + c) * DD + t] = nv;
    unsigned short hb = f2bf(nv);
    unsigned short lb = f2bf(nv - bf2f(hb));
    size_t idx = (size_t)s * 16384 + fragidx(c, t);
    chi[idx] = (short)hb;
    clo[idx] = (short)lb;
    red[t] = nv * nv;
    __syncthreads();
    for (int w = 128; w > 0; w >>= 1) {
        if (t < w) red[t] += red[t + w];
        __syncthreads();
    }
    if (t == 0) cnorm[s * CC + c] = red[0];
}

// ---------------------------------------------------------------- MFMA approx GEMM + per-row candidate top-8x2 per split
// Round-17 showed FETCH=521MB (A-frag L2 thrash: 64 resident blocks x
// 128KB private A > 4MB per-XCD L2, re-read every ct pass). Fix: BM=64,
// A hi/lo (64KB, contiguous in frag-linear layout) staged ONCE into LDS;
// K-loop reads A via conflict-free contiguous ds_read. B stays global
// (1MB per XCD, L2-resident; grid keeps XCD%8==split). Per-(row,col)
// MFMA chains, sh-based column partition, candidate dump all bitwise
// identical to the proven version.
__global__ __launch_bounds__(256) void topk_gemm_k(const short* __restrict__ shi,
                                                   const short* __restrict__ slo,
                                                   const short* __restrict__ thi,
                                                   const short* __restrict__ tlo,
                                                   float* __restrict__ pv,
                                                   int* __restrict__ pi) {
    __shared__ short Ah[16384];       // 32 KB: 4 row-tiles x 8 S x 512
    __shared__ short Al[16384];       // 32 KB
    __shared__ float scanb[BM * BN];  // 16 KB C-tile scan buffer

    const int split = blockIdx.x;
    const int rowB = blockIdx.y * BM;
    const int tid = threadIdx.x;
    const int w = tid >> 6;
    const int lane = tid & 63;
    const int rl = lane & 15;
    const int lh = lane >> 4;

    // stage A frag-tiles for rows [rowB, rowB+64): contiguous 32KB chunks
    {
        const int TA0 = rowB >> 4;
        const short* gH = shi + (size_t)TA0 * 4096;
        const short* gL = slo + (size_t)TA0 * 4096;
        for (int u = tid; u < 2048; u += 256) {
            *(short8v*)&Ah[u * 8] = *(const short8v*)&gH[(size_t)u * 8];
            *(short8v*)&Al[u * 8] = *(const short8v*)&gL[(size_t)u * 8];
        }
    }
    __syncthreads();

    float tv[TK];
    int ti[TK];
#pragma unroll
    for (int q = 0; q < TK; q++) { tv[q] = -INFINITY; ti[q] = 0x7fffffff; }

    const int colBase = split * (NN / CSPLIT);

#pragma unroll 1
    for (int ct = 0; ct < (NN / CSPLIT) / BN; ct++) {
        const int colB = colBase + ct * BN;
        const int U0 = colB >> 4;
        f32x4 acc[4];
#pragma unroll
        for (int ut = 0; ut < 4; ut++) acc[ut] = (f32x4){0.f, 0.f, 0.f, 0.f};

#pragma unroll 1
        for (int S = 0; S < 8; S++) {
            short8v ah = *(const short8v*)&Ah[((w * 8 + S) * 64 + lane) * 8];
            short8v al = *(const short8v*)&Al[((w * 8 + S) * 64 + lane) * 8];
#pragma unroll
            for (int ut = 0; ut < 4; ut++) {
                const size_t boff = ((size_t)((U0 + ut) * 8 + S) * 64 + lane) * 8;
                short8v bh = *(const short8v*)(thi + boff);
                short8v bl = *(const short8v*)(tlo + boff);
                acc[ut] = MFMA(ah, bh, acc[ut]);
                acc[ut] = MFMA(ah, bl, acc[ut]);
                acc[ut] = MFMA(al, bh, acc[ut]);
            }
        }
        __syncthreads();  // previous scan reads done
        // C write (swizzled, +diag boost on approx value to force self in)
#pragma unroll
        for (int ut = 0; ut < 4; ut++)
#pragma unroll
            for (int reg = 0; reg < 4; reg++) {
                int r_loc = 16 * w + 4 * lh + reg;
                int cl = 16 * ut + rl;
                float v = acc[ut][reg];
                if (rowB + r_loc == colB + cl) v += 10.f;
                scanb[r_loc * 64 + (cl ^ (r_loc & 31))] = v;
            }
        __syncthreads();
        // per-thread approx top-8 over 32 of this tile's 64 columns
        if (tid < 128) {
            const int sr = tid >> 1;  // row 0..63
            const int sh = tid & 1;
#pragma unroll 4
            for (int c = 0; c < 32; c++) {
                int cb2 = sh * 32 + c;
                float v = scanb[sr * 64 + (cb2 ^ (sr & 31))];
                int gcol = colB + cb2;
                if (kbetter(v, gcol, tv[TK - 1], ti[TK - 1])) {
                    tv[TK - 1] = v;
                    ti[TK - 1] = gcol;
#pragma unroll
                    for (int q = TK - 1; q > 0; --q) {
                        if (kbetter(tv[q], ti[q], tv[q - 1], ti[q - 1])) {
                            float t1 = tv[q]; tv[q] = tv[q - 1]; tv[q - 1] = t1;
                            int t2 = ti[q]; ti[q] = ti[q - 1]; ti[q - 1] = t2;
                        }
                    }
                }
            }
        }
    }
    // dump both halves' top-8 as this split's 16 candidates for the row
    if (tid < 128) {
        const int sr = tid >> 1;
        const int sh = tid & 1;
        int row = rowB + sr;
#pragma unroll
        for (int q = 0; q < TK; q++) {
            pv[((size_t)row * CSPLIT + split) * 16 + sh * 8 + q] = tv[q];
            pi[((size_t)row * CSPLIT + split) * 16 + sh * 8 + q] = ti[q];
        }
    }
}

// ---------------------------------------------------------------- merge 128 approx candidates -> top-24 per row
// (proven round 13) Wave-per-row parallel selection via u64 keys.
__global__ __launch_bounds__(256) void topk_merge_k(const float* __restrict__ pv,
                                                    const int* __restrict__ pi,
                                                    int* __restrict__ cand) {
    const int tid = threadIdx.x;
    const int wid = tid >> 6;
    const int lane = tid & 63;
    const int row = blockIdx.x * 4 + wid;
    const size_t base = (size_t)row * (CSPLIT * 16);

    float v0 = pv[base + lane];
    float v1 = pv[base + 64 + lane];
    unsigned i0 = (unsigned)pi[base + lane];
    unsigned i1 = (unsigned)pi[base + 64 + lane];
    unsigned s0 = __float_as_uint(v0);
    unsigned s1 = __float_as_uint(v1);
    unsigned m0 = (s0 & 0x80000000u) ? ~s0 : (s0 | 0x80000000u);
    unsigned m1 = (s1 & 0x80000000u) ? ~s1 : (s1 | 0x80000000u);
    unsigned long long k0 = (((unsigned long long)m0) << 32) | (0xFFFFFFFFu - i0);
    unsigned long long k1 = (((unsigned long long)m1) << 32) | (0xFFFFFFFFu - i1);

    for (int o = 0; o < NCAND; o++) {
        unsigned long long m = k0 > k1 ? k0 : k1;
#pragma unroll
        for (int off = 32; off > 0; off >>= 1) {
            unsigned long long other = __shfl_xor(m, off, 64);
            if (other > m) m = other;
        }
        if (lane == 0)
            cand[row * NCAND + o] = (int)(0xFFFFFFFFu - (unsigned)(m & 0xFFFFFFFFu));
        if (k0 == m) k0 = 0;
        if (k1 == m) k1 = 0;
    }
}

// ---------------------------------------------------------------- exact rescore of candidates -> final top-8
__global__ __launch_bounds__(256) void rescore_k(const float* __restrict__ student,
                                                 const float* __restrict__ teacher,
                                                 const int* __restrict__ cand,
                                                 int* __restrict__ iknn,
                                                 float* __restrict__ dknn) {
    __shared__ float srow[4 * DD];     // 4 student rows
    __shared__ int clist[4 * NCAND];
    __shared__ float cv[4 * NCAND];
    __shared__ int civ[4 * NCAND];
    const int tid = threadIdx.x;
    const int r0 = blockIdx.x * 4;
    *(float4*)&srow[tid * 4] = *(const float4*)&student[(size_t)r0 * DD + tid * 4];
    for (int i = tid; i < 4 * NCAND; i += 256) clist[i] = cand[r0 * NCAND + i];
    __syncthreads();
    const int w = tid >> 6;
    const int lane = tid & 63;
    const int r = r0 + w;
    if (lane < NCAND) {
        int c = clist[w * NCAND + lane];
        const float* tr = teacher + (size_t)c * DD;
        const float* sw = srow + w * DD;
        float acc = 0.f;
#pragma unroll 8
        for (int k = 0; k < DD; k += 4) {
            float4 t4 = *(const float4*)&tr[k];
            acc = fmaf(sw[k], t4.x, acc);
            acc = fmaf(sw[k + 1], t4.y, acc);
            acc = fmaf(sw[k + 2], t4.z, acc);
            acc = fmaf(sw[k + 3], t4.w, acc);
        }
        if (c == r) acc += 10.f;
        cv[w * NCAND + lane] = acc;
        civ[w * NCAND + lane] = c;
    }
    __syncthreads();
    if (lane == 0) {
        unsigned used = 0;
        for (int o = 0; o < TK; o++) {
            float bv = -INFINITY;
            int bi = 0x7fffffff;
            int bsel = -1;
            for (int m = 0; m < NCAND; m++) {
                if ((used >> m) & 1u) continue;
                float v = cv[w * NCAND + m];
                int ix = civ[w * NCAND + m];
                if (bsel < 0 || kbetter(v, ix, bv, bi)) { bv = v; bi = ix; bsel = m; }
            }
            used |= 1u << bsel;
            iknn[r * TK + o] = bi;
            dknn[r * TK + o] = bv;
        }
    }
}

// ---------------------------------------------------------------- epilogue: masks + output
__global__ __launch_bounds__(256) void out_k(const int* __restrict__ iknn,
                                             const float* __restrict__ dknn,
                                             const unsigned int* __restrict__ bm,
                                             const int* __restrict__ labels,
                                             float* __restrict__ out) {
    int t = blockIdx.x * 256 + threadIdx.x;
    int row = t >> 3;
    int ki = iknn[t];
    unsigned code = (unsigned)row * NN + (unsigned)ki;
    bool adj = (bm[code >> 5] >> (code & 31)) & 1u;
    bool close = false;
#pragma unroll
    for (int s = 0; s < KSEED; s++)
        close |= (labels[s * NN + row] == labels[s * NN + ki]);
    out[t] = (float)ki;
    out[NN * TK + t] = (adj || close) ? 1.0f : 0.0f;
    out[2 * NN * TK + t] = dknn[t];
}

// ----------------------------------------------------------------
extern "C" void kernel_launch(void* const* d_in, const int* in_sizes, int n_in,
                              void* d_out, int out_size, void* d_ws, size_t ws_size,
                              hipStream_t stream) {
    (void)n_in; (void)out_size; (void)ws_size;
    const float* student = (const float*)d_in[0];
    const float* teacher = (const float*)d_in[1];
    const int* edge = (const int*)d_in[2];
    const int* initIdx = (const int*)d_in[3];
    const int E = in_sizes[2] / 2;

    char* ws = (char*)d_ws;
    size_t off = 0;
    auto alloc = [&](size_t bytes) -> char* {
        char* p = ws + off;
        off += (bytes + 255) & ~(size_t)255;
        return p;
    };
    unsigned int* bm = (unsigned int*)alloc((size_t)NN * NN / 8);      // 8 MB
    short* shi = (short*)alloc((size_t)NN * DD * 2);                   // 4 MB
    short* slo = (short*)alloc((size_t)NN * DD * 2);
    short* thi = (short*)alloc((size_t)NN * DD * 2);
    short* tlo = (short*)alloc((size_t)NN * DD * 2);
    float* centR = (float*)alloc((size_t)KSEED * CC * DD * 4);         // 320 KB
    float* cnorm = (float*)alloc((size_t)KSEED * CC * 4);
    short* chi = (short*)alloc((size_t)KSEED * 16384 * 2);             // 160 KB
    short* clo = (short*)alloc((size_t)KSEED * 16384 * 2);
    int* labels = (int*)alloc((size_t)KSEED * NN * 4);
    float* pv = (float*)alloc((size_t)NN * CSPLIT * 16 * 4);           // 4 MB
    int* pi = (int*)alloc((size_t)NN * CSPLIT * 16 * 4);               // 4 MB
    int* cand = (int*)alloc((size_t)NN * NCAND * 4);
    int* iknn = (int*)alloc((size_t)NN * TK * 4);
    float* dknn = (float*)alloc((size_t)NN * TK * 4);
    float* out = (float*)d_out;

    hipMemsetAsync(bm, 0, (size_t)NN * NN / 8, stream);
    adj_k<<<dim3((E + 255) / 256), 256, 0, stream>>>(edge, edge + E, bm, E);
    conv_k<<<dim3(NN * DD / 8 / 256), 256, 0, stream>>>(student, shi, slo);
    conv_k<<<dim3(NN * DD / 8 / 256), 256, 0, stream>>>(teacher, thi, tlo);

    kinit_k<<<dim3(CC, KSEED), 256, 0, stream>>>(teacher, initIdx, centR, cnorm, chi, clo);
    for (int it = 0; it < NITERS; ++it) {
        kassign_k<<<dim3(NN / 64, KSEED), 256, 0, stream>>>(teacher, thi, tlo, chi, clo,
                                                            centR, cnorm, labels);
        kupd12_k<<<dim3(CC, KSEED), 256, 0, stream>>>(teacher, labels, centR, cnorm, chi, clo);
    }
    kassign_k<<<dim3(NN / 64, KSEED), 256, 0, stream>>>(teacher, thi, tlo, chi, clo,
                                                        centR, cnorm, labels);

    topk_gemm_k<<<dim3(CSPLIT, NN / BM), 256, 0, stream>>>(shi, slo, thi, tlo, pv, pi);
    topk_merge_k<<<dim3(NN / 4), 256, 0, stream>>>(pv, pi, cand);
    rescore_k<<<dim3(NN / 4), 256, 0, stream>>>(student, teacher, cand, iknn, dknn);
    out_k<<<dim3(NN * TK / 256), 256, 0, stream>>>(iknn, dknn, bm, labels, out);
}

// Round 19
// 1837.685 us; speedup vs baseline: 1.3124x; 1.3124x over previous
//
#include <hip/hip_runtime.h>
#include <hip/hip_bf16.h>
#include <math.h>

#define NN 8192
#define DD 256
#define KSEED 5
#define CC 64
#define TK 8
#define NITERS 20
#define CSPLIT 8
#define BM 128
#define BN 64
#define UB 32    // kupd12 gather batch rows
#define NCAND 24 // rescore candidates per row

typedef __attribute__((ext_vector_type(8))) short short8v;
typedef __attribute__((ext_vector_type(4))) float f32x4;

#define MFMA(a, b, c) __builtin_amdgcn_mfma_f32_16x16x32_bf16(a, b, c, 0, 0, 0)

__device__ __forceinline__ bool kbetter(float v1, int i1, float v2, int i2) {
    return (v1 > v2) || ((v1 == v2) && (i1 < i2));
}

__device__ __forceinline__ unsigned short f2bf(float x) {  // RNE
    unsigned u = __float_as_uint(x);
    unsigned r = 0x7fffu + ((u >> 16) & 1u);
    return (unsigned short)((u + r) >> 16);
}
__device__ __forceinline__ float bf2f(unsigned short h) {
    return __uint_as_float(((unsigned)h) << 16);
}

// ---------------------------------------------------------------- transpose
// in [NN][DD] -> out [DD][NN]  (teacher only; kassign needs it)
__global__ __launch_bounds__(256) void transpose_k(const float* __restrict__ in,
                                                   float* __restrict__ out) {
    __shared__ float t[32][33];
    int bx = blockIdx.x * 32;
    int by = blockIdx.y * 32;
    int x = threadIdx.x;
    int y = threadIdx.y;
#pragma unroll
    for (int i = 0; i < 32; i += 8)
        t[y + i][x] = in[(size_t)(bx + y + i) * DD + by + x];
    __syncthreads();
#pragma unroll
    for (int i = 0; i < 32; i += 8)
        out[(size_t)(by + y + i) * NN + bx + x] = t[x][y + i];
}

// ---------------------------------------------------------------- adjacency bitmap
__global__ __launch_bounds__(256) void adj_k(const int* __restrict__ e0,
                                             const int* __restrict__ e1,
                                             unsigned int* __restrict__ bm, int E) {
    int t = blockIdx.x * 256 + threadIdx.x;
    if (t < E) {
        unsigned code = (unsigned)e0[t] * NN + (unsigned)e1[t];
        atomicOr(&bm[code >> 5], 1u << (code & 31));
    }
}

// ---------------------------------------------------------------- bf16 hi/lo split, fragment-linear layout
// element (r,k) with r=16T+(l&15), k=32S+8*(l>>4)+j lives at
// [((T*8+S)*64+l)*8+j]: a wave's MFMA fragment load is one contiguous
// 1KB dwordx4 at lane*16B -- coalesced, no LDS needed.
__global__ __launch_bounds__(256) void conv_k(const float* __restrict__ src,
                                              short* __restrict__ hi,
                                              short* __restrict__ lo) {
    int slot = blockIdx.x * 256 + threadIdx.x;  // 0..262143
    int l = slot & 63;
    int TS = slot >> 6;
    int S = TS & 7;
    int T = TS >> 3;
    int row = T * 16 + (l & 15);
    int k0 = S * 32 + (l >> 4) * 8;
    const float* p = src + (size_t)row * DD + k0;
    short8v h8, l8;
#pragma unroll
    for (int j = 0; j < 8; j++) {
        float x = p[j];
        unsigned short hb = f2bf(x);
        unsigned short lb = f2bf(x - bf2f(hb));
        h8[j] = (short)hb;
        l8[j] = (short)lb;
    }
    *(short8v*)(hi + (size_t)slot * 8) = h8;
    *(short8v*)(lo + (size_t)slot * 8) = l8;
}

// ---------------------------------------------------------------- kmeans init
// centT layout: [s][d][c]
__global__ __launch_bounds__(256) void kinit_k(const float* __restrict__ teacher,
                                               const int* __restrict__ initIdx,
                                               float* __restrict__ centT,
                                               float* __restrict__ cnorm) {
    int c = blockIdx.x, s = blockIdx.y;
    int t = threadIdx.x;
    int src = initIdx[s * CC + c];
    float v = teacher[(size_t)src * DD + t];
    centT[((size_t)s * DD + t) * CC + c] = v;
    __shared__ float red[256];
    red[t] = v * v;
    __syncthreads();
    for (int w = 128; w > 0; w >>= 1) {
        if (t < w) red[t] += red[t + w];
        __syncthreads();
    }
    if (t == 0) cnorm[s * CC + c] = red[0];
}

// ---------------------------------------------------------------- kmeans assign (proven; kt loop kept rolled for I$)
__global__ __launch_bounds__(256) void kassign_k(const float* __restrict__ tT,
                                                 const float* __restrict__ centT,
                                                 const float* __restrict__ cnorm,
                                                 int* __restrict__ labels) {
    __shared__ float Xs[64 * 64];
    __shared__ float Cs[64 * 64];
    const int s = blockIdx.y;
    const int pB = blockIdx.x * 64;
    const int tid = threadIdx.x;
    const int tx = tid & 15;
    const int ty = tid >> 4;
    float acc[4][4];
#pragma unroll
    for (int a = 0; a < 4; a++)
#pragma unroll
        for (int b = 0; b < 4; b++) acc[a][b] = 0.f;

#pragma unroll 1
    for (int kt = 0; kt < DD; kt += 64) {
        __syncthreads();
#pragma unroll
        for (int m = 0; m < 4; m++) {
            int u = m * 256 + tid;
            int kk = u >> 4;
            int p4 = (u & 15) << 2;
            *(float4*)&Xs[kk * 64 + p4] =
                *(const float4*)&tT[(size_t)(kt + kk) * NN + pB + p4];
            *(float4*)&Cs[kk * 64 + p4] =
                *(const float4*)&centT[((size_t)s * DD + kt + kk) * CC + p4];
        }
        __syncthreads();
#pragma unroll 8
        for (int kk = 0; kk < 64; kk++) {
            float4 x4 = *(float4*)&Xs[kk * 64 + 4 * ty];
            float4 c4 = *(float4*)&Cs[kk * 64 + 4 * tx];
            float xr[4] = {x4.x, x4.y, x4.z, x4.w};
            float cr[4] = {c4.x, c4.y, c4.z, c4.w};
#pragma unroll
            for (int a = 0; a < 4; a++)
#pragma unroll
                for (int b = 0; b < 4; b++) acc[a][b] = fmaf(xr[a], cr[b], acc[a][b]);
        }
    }
    __syncthreads();
    float* red = Cs;
    float cn[4];
#pragma unroll
    for (int b = 0; b < 4; b++) cn[b] = cnorm[s * CC + 4 * tx + b];
#pragma unroll
    for (int a = 0; a < 4; a++) {
        float bv = INFINITY;
        int bc = 0;
#pragma unroll
        for (int b = 0; b < 4; b++) {
            float d = fmaf(-2.f, acc[a][b], cn[b]);
            if (d < bv) { bv = d; bc = 4 * tx + b; }
        }
        int p = 4 * ty + a;
        red[(p * 16 + tx) * 2] = bv;
        ((int*)red)[(p * 16 + tx) * 2 + 1] = bc;
    }
    __syncthreads();
    if (tid < 64) {
        float bv = INFINITY;
        int bc = 0;
        for (int t2 = 0; t2 < 16; t2++) {
            float v = red[(tid * 16 + t2) * 2];
            int c = ((int*)red)[(tid * 16 + t2) * 2 + 1];
            if (v < bv) { bv = v; bc = c; }
        }
        labels[(size_t)s * NN + pB + tid] = bc;
    }
}

// ---------------------------------------------------------------- fused kmeans update (proven, round 11)
__global__ __launch_bounds__(256) void kupd12_k(const float* __restrict__ teacher,
                                                const int* __restrict__ labels,
                                                float* __restrict__ centT,
                                                float* __restrict__ cnorm) {
    const int c = blockIdx.x;
    const int s = blockIdx.y;
    const int t = threadIdx.x;
    __shared__ int list[NN];
    __shared__ float stage[UB * DD];
    __shared__ int scan_s[256];
    __shared__ float red[256];
    __shared__ int total_s;

    const int* labS = labels + (size_t)s * NN;

    int my = 0;
#pragma unroll
    for (int j = 0; j < 32; j++) my += (labS[t * 32 + j] == c);
    scan_s[t] = my;
    __syncthreads();
    for (int off = 1; off < 256; off <<= 1) {
        int v = (t >= off) ? scan_s[t - off] : 0;
        __syncthreads();
        scan_s[t] += v;
        __syncthreads();
    }
    const int base = scan_s[t] - my;
    if (t == 255) total_s = scan_s[255];
    int pos = base;
#pragma unroll
    for (int j = 0; j < 32; j++) {
        int p = t * 32 + j;
        if (labS[p] == c) list[pos++] = p;
    }
    __syncthreads();
    const int total = total_s;

    float sum = 0.f, part = 0.f;
    int curb = 0;
    for (int g0 = 0; g0 < total; g0 += UB) {
        const int gn = (total - g0 < UB) ? (total - g0) : UB;
        __syncthreads();
        for (int u = t; u < gn * (DD / 4); u += 256) {
            int j = u >> 6;
            int col4 = (u & 63) << 2;
            *(float4*)&stage[j * DD + col4] =
                *(const float4*)&teacher[(size_t)list[g0 + j] * DD + col4];
        }
        __syncthreads();
        for (int j = 0; j < gn; j++) {
            int p = list[g0 + j];
            int b = p >> 8;
            while (curb < b) { sum += part; part = 0.f; curb++; }
            part += stage[j * DD + t];
        }
    }
    while (curb < 32) { sum += part; part = 0.f; curb++; }

    float old = centT[((size_t)s * DD + t) * CC + c];
    float nv = (total > 0) ? (sum / (float)total) : old;
    centT[((size_t)s * DD + t) * CC + c] = nv;
    red[t] = nv * nv;
    __syncthreads();
    for (int w = 128; w > 0; w >>= 1) {
        if (t < w) red[t] += red[t + w];
        __syncthreads();
    }
    if (t == 0) cnorm[s * CC + c] = red[0];
}

// ---------------------------------------------------------------- MFMA approx GEMM + per-row candidate top-8x2 per split
// (proven rounds 12-14, absmax 0.0)
// ct loop kept ROLLED (#pragma unroll 1): the fully-unrolled 16x body
// (~250 KB) thrashed the 32 KB L1I -> all pipes idle at 660 us. B-frags
// loaded per-ut (live B regs 64 -> 8; VGPR under the 128 wave-slot
// quantum). acc[rt][ut] chains are the identical 3-pass x 8-S MFMA
// sequence -> identical candidates -> bitwise-identical final output.
// NOTE (round 18): this kernel is VALU/scan-bound (VALUBusy 73%), NOT
// bandwidth-bound (1.29 TB/s << 6.3 peak despite FETCH 521 MB); the
// BM=64 LDS-staged variant cut FETCH 13x but regressed 421->677 us by
// halving scan parallelism. Keep this version.
__global__ __launch_bounds__(256) void topk_gemm_k(const short* __restrict__ shi,
                                                   const short* __restrict__ slo,
                                                   const short* __restrict__ thi,
                                                   const short* __restrict__ tlo,
                                                   float* __restrict__ pv,
                                                   int* __restrict__ pi) {
    __shared__ float smem[BM * BN];  // 32 KB C-tile scan buffer

    const int split = blockIdx.x;
    const int rowB = blockIdx.y * BM;
    const int tid = threadIdx.x;
    const int w = tid >> 6;
    const int lane = tid & 63;
    const int rl = lane & 15;
    const int lh = lane >> 4;
    const int sr = tid >> 1;  // scan row 0..127
    const int sh = tid & 1;   // scan half (32 cols)

    float tv[TK];
    int ti[TK];
#pragma unroll
    for (int q = 0; q < TK; q++) { tv[q] = -INFINITY; ti[q] = 0x7fffffff; }

    const int colBase = split * (NN / CSPLIT);
    const int TA0 = (rowB >> 4) + 2 * w;  // A-tile index, rt=0

#pragma unroll 1
    for (int ct = 0; ct < (NN / CSPLIT) / BN; ct++) {
        const int colB = colBase + ct * BN;
        const int U0 = colB >> 4;
        f32x4 acc[2][4];
#pragma unroll
        for (int rt = 0; rt < 2; rt++)
#pragma unroll
            for (int ut = 0; ut < 4; ut++) acc[rt][ut] = (f32x4){0.f, 0.f, 0.f, 0.f};

#pragma unroll 1
        for (int S = 0; S < 8; S++) {
            const size_t a0off = ((size_t)(TA0 * 8 + S) * 64 + lane) * 8;
            const size_t a1off = ((size_t)((TA0 + 1) * 8 + S) * 64 + lane) * 8;
            short8v ah0 = *(const short8v*)(shi + a0off);
            short8v ah1 = *(const short8v*)(shi + a1off);
            short8v al0 = *(const short8v*)(slo + a0off);
            short8v al1 = *(const short8v*)(slo + a1off);
#pragma unroll
            for (int ut = 0; ut < 4; ut++) {
                const size_t boff = ((size_t)((U0 + ut) * 8 + S) * 64 + lane) * 8;
                short8v bh = *(const short8v*)(thi + boff);
                short8v bl = *(const short8v*)(tlo + boff);
                acc[0][ut] = MFMA(ah0, bh, acc[0][ut]);
                acc[0][ut] = MFMA(ah0, bl, acc[0][ut]);
                acc[0][ut] = MFMA(al0, bh, acc[0][ut]);
                acc[1][ut] = MFMA(ah1, bh, acc[1][ut]);
                acc[1][ut] = MFMA(ah1, bl, acc[1][ut]);
                acc[1][ut] = MFMA(al1, bh, acc[1][ut]);
            }
        }
        __syncthreads();  // previous scan reads done
        // C write (swizzled, +diag boost on approx value to force self in)
#pragma unroll
        for (int rt = 0; rt < 2; rt++)
#pragma unroll
            for (int ut = 0; ut < 4; ut++)
#pragma unroll
                for (int reg = 0; reg < 4; reg++) {
                    int r_loc = 32 * w + 16 * rt + 4 * lh + reg;
                    int cl = 16 * ut + rl;
                    float v = acc[rt][ut][reg];
                    if (rowB + r_loc == colB + cl) v += 10.f;
                    smem[r_loc * 64 + (cl ^ (r_loc & 31))] = v;
                }
        __syncthreads();
        // per-thread approx top-8 over 32 of this tile's 64 columns
#pragma unroll 4
        for (int c = 0; c < 32; c++) {
            int cb2 = sh * 32 + c;
            float v = smem[sr * 64 + (cb2 ^ (sr & 31))];
            int gcol = colB + cb2;
            if (kbetter(v, gcol, tv[TK - 1], ti[TK - 1])) {
                tv[TK - 1] = v;
                ti[TK - 1] = gcol;
#pragma unroll
                for (int q = TK - 1; q > 0; --q) {
                    if (kbetter(tv[q], ti[q], tv[q - 1], ti[q - 1])) {
                        float t1 = tv[q]; tv[q] = tv[q - 1]; tv[q - 1] = t1;
                        int t2 = ti[q]; ti[q] = ti[q - 1]; ti[q - 1] = t2;
                    }
                }
            }
        }
    }
    // dump both halves' top-8 as this split's 16 candidates for the row
    int row = rowB + sr;
#pragma unroll
    for (int q = 0; q < TK; q++) {
        pv[((size_t)row * CSPLIT + split) * 16 + sh * 8 + q] = tv[q];
        pi[((size_t)row * CSPLIT + split) * 16 + sh * 8 + q] = ti[q];
    }
}

// ---------------------------------------------------------------- merge 128 approx candidates -> top-24 per row
// (proven round 13) Wave-per-row parallel selection via u64 keys.
__global__ __launch_bounds__(256) void topk_merge_k(const float* __restrict__ pv,
                                                    const int* __restrict__ pi,
                                                    int* __restrict__ cand) {
    const int tid = threadIdx.x;
    const int wid = tid >> 6;
    const int lane = tid & 63;
    const int row = blockIdx.x * 4 + wid;
    const size_t base = (size_t)row * (CSPLIT * 16);

    float v0 = pv[base + lane];
    float v1 = pv[base + 64 + lane];
    unsigned i0 = (unsigned)pi[base + lane];
    unsigned i1 = (unsigned)pi[base + 64 + lane];
    unsigned s0 = __float_as_uint(v0);
    unsigned s1 = __float_as_uint(v1);
    unsigned m0 = (s0 & 0x80000000u) ? ~s0 : (s0 | 0x80000000u);
    unsigned m1 = (s1 & 0x80000000u) ? ~s1 : (s1 | 0x80000000u);
    unsigned long long k0 = (((unsigned long long)m0) << 32) | (0xFFFFFFFFu - i0);
    unsigned long long k1 = (((unsigned long long)m1) << 32) | (0xFFFFFFFFu - i1);

    for (int o = 0; o < NCAND; o++) {
        unsigned long long m = k0 > k1 ? k0 : k1;
#pragma unroll
        for (int off = 32; off > 0; off >>= 1) {
            unsigned long long other = __shfl_xor(m, off, 64);
            if (other > m) m = other;
        }
        if (lane == 0)
            cand[row * NCAND + o] = (int)(0xFFFFFFFFu - (unsigned)(m & 0xFFFFFFFFu));
        if (k0 == m) k0 = 0;
        if (k1 == m) k1 = 0;
    }
}

// ---------------------------------------------------------------- exact rescore of candidates -> final top-8
// Exact value = the SAME ascending-k fmaf chain (+10 diag after) the fp32
// kernel used for 11 rounds -> bitwise-identical outputs given the
// candidate superset.
__global__ __launch_bounds__(256) void rescore_k(const float* __restrict__ student,
                                                 const float* __restrict__ teacher,
                                                 const int* __restrict__ cand,
                                                 int* __restrict__ iknn,
                                                 float* __restrict__ dknn) {
    __shared__ float srow[4 * DD];     // 4 student rows
    __shared__ int clist[4 * NCAND];
    __shared__ float cv[4 * NCAND];
    __shared__ int civ[4 * NCAND];
    const int tid = threadIdx.x;
    const int r0 = blockIdx.x * 4;
    *(float4*)&srow[tid * 4] = *(const float4*)&student[(size_t)r0 * DD + tid * 4];
    for (int i = tid; i < 4 * NCAND; i += 256) clist[i] = cand[r0 * NCAND + i];
    __syncthreads();
    const int w = tid >> 6;
    const int lane = tid & 63;
    const int r = r0 + w;
    if (lane < NCAND) {
        int c = clist[w * NCAND + lane];
        const float* tr = teacher + (size_t)c * DD;
        const float* sw = srow + w * DD;
        float acc = 0.f;
#pragma unroll 8
        for (int k = 0; k < DD; k += 4) {
            float4 t4 = *(const float4*)&tr[k];
            acc = fmaf(sw[k], t4.x, acc);
            acc = fmaf(sw[k + 1], t4.y, acc);
            acc = fmaf(sw[k + 2], t4.z, acc);
            acc = fmaf(sw[k + 3], t4.w, acc);
        }
        if (c == r) acc += 10.f;
        cv[w * NCAND + lane] = acc;
        civ[w * NCAND + lane] = c;
    }
    __syncthreads();
    if (lane == 0) {
        unsigned used = 0;
        for (int o = 0; o < TK; o++) {
            float bv = -INFINITY;
            int bi = 0x7fffffff;
            int bsel = -1;
            for (int m = 0; m < NCAND; m++) {
                if ((used >> m) & 1u) continue;
                float v = cv[w * NCAND + m];
                int ix = civ[w * NCAND + m];
                if (bsel < 0 || kbetter(v, ix, bv, bi)) { bv = v; bi = ix; bsel = m; }
            }
            used |= 1u << bsel;
            iknn[r * TK + o] = bi;
            dknn[r * TK + o] = bv;
        }
    }
}

// ---------------------------------------------------------------- epilogue: masks + output
__global__ __launch_bounds__(256) void out_k(const int* __restrict__ iknn,
                                             const float* __restrict__ dknn,
                                             const unsigned int* __restrict__ bm,
                                             const int* __restrict__ labels,
                                             float* __restrict__ out) {
    int t = blockIdx.x * 256 + threadIdx.x;
    int row = t >> 3;
    int ki = iknn[t];
    unsigned code = (unsigned)row * NN + (unsigned)ki;
    bool adj = (bm[code >> 5] >> (code & 31)) & 1u;
    bool close = false;
#pragma unroll
    for (int s = 0; s < KSEED; s++)
        close |= (labels[s * NN + row] == labels[s * NN + ki]);
    out[t] = (float)ki;
    out[NN * TK + t] = (adj || close) ? 1.0f : 0.0f;
    out[2 * NN * TK + t] = dknn[t];
}

// ----------------------------------------------------------------
extern "C" void kernel_launch(void* const* d_in, const int* in_sizes, int n_in,
                              void* d_out, int out_size, void* d_ws, size_t ws_size,
                              hipStream_t stream) {
    (void)n_in; (void)out_size; (void)ws_size;
    const float* student = (const float*)d_in[0];
    const float* teacher = (const float*)d_in[1];
    const int* edge = (const int*)d_in[2];
    const int* initIdx = (const int*)d_in[3];
    const int E = in_sizes[2] / 2;

    char* ws = (char*)d_ws;
    size_t off = 0;
    auto alloc = [&](size_t bytes) -> char* {
        char* p = ws + off;
        off += (bytes + 255) & ~(size_t)255;
        return p;
    };
    unsigned int* bm = (unsigned int*)alloc((size_t)NN * NN / 8);      // 8 MB
    float* tT = (float*)alloc((size_t)NN * DD * 4);                    // 8 MB
    short* shi = (short*)alloc((size_t)NN * DD * 2);                   // 4 MB
    short* slo = (short*)alloc((size_t)NN * DD * 2);
    short* thi = (short*)alloc((size_t)NN * DD * 2);
    short* tlo = (short*)alloc((size_t)NN * DD * 2);
    float* centT = (float*)alloc((size_t)KSEED * DD * CC * 4);
    float* cnorm = (float*)alloc((size_t)KSEED * CC * 4);
    int* labels = (int*)alloc((size_t)KSEED * NN * 4);
    float* pv = (float*)alloc((size_t)NN * CSPLIT * 16 * 4);           // 4 MB
    int* pi = (int*)alloc((size_t)NN * CSPLIT * 16 * 4);               // 4 MB
    int* cand = (int*)alloc((size_t)NN * NCAND * 4);
    int* iknn = (int*)alloc((size_t)NN * TK * 4);
    float* dknn = (float*)alloc((size_t)NN * TK * 4);
    float* out = (float*)d_out;

    hipMemsetAsync(bm, 0, (size_t)NN * NN / 8, stream);
    adj_k<<<dim3((E + 255) / 256), 256, 0, stream>>>(edge, edge + E, bm, E);
    transpose_k<<<dim3(NN / 32, DD / 32), dim3(32, 8), 0, stream>>>(teacher, tT);
    conv_k<<<dim3(NN * DD / 8 / 256), 256, 0, stream>>>(student, shi, slo);
    conv_k<<<dim3(NN * DD / 8 / 256), 256, 0, stream>>>(teacher, thi, tlo);

    kinit_k<<<dim3(CC, KSEED), 256, 0, stream>>>(teacher, initIdx, centT, cnorm);
    for (int it = 0; it < NITERS; ++it) {
        kassign_k<<<dim3(NN / 64, KSEED), 256, 0, stream>>>(tT, centT, cnorm, labels);
        kupd12_k<<<dim3(CC, KSEED), 256, 0, stream>>>(teacher, labels, centT, cnorm);
    }
    kassign_k<<<dim3(NN / 64, KSEED), 256, 0, stream>>>(tT, centT, cnorm, labels);

    topk_gemm_k<<<dim3(CSPLIT, NN / BM), 256, 0, stream>>>(shi, slo, thi, tlo, pv, pi);
    topk_merge_k<<<dim3(NN / 4), 256, 0, stream>>>(pv, pi, cand);
    rescore_k<<<dim3(NN / 4), 256, 0, stream>>>(student, teacher, cand, iknn, dknn);
    out_k<<<dim3(NN * TK / 256), 256, 0, stream>>>(iknn, dknn, bm, labels, out);
}